// Round 8
// baseline (176.859 us; speedup 1.0000x reference)
//
#include <hip/hip_runtime.h>
#include <math.h>

// Shapes (fixed by the reference setup)
#define D 64
#define E 128
#define H 256
#define N 128
#define H2 512          // drive hidden + resistance hidden concatenated
#define SIXD 384
#define INV_SIXD 0.0026041666666666665f

__device__ __forceinline__ float fast_erff(float x) {
    float ax = fabsf(x);
    float t = __builtin_amdgcn_rcpf(fmaf(0.3275911f, ax, 1.0f));
    float p = t * fmaf(t, fmaf(t, fmaf(t, fmaf(t, 1.061405429f, -1.453152027f),
                               1.421413741f), -0.284496736f), 0.254829592f);
    float r = fmaf(-p, __expf(-ax * ax), 1.0f);
    return copysignf(r, x);
}

__device__ __forceinline__ float fast_gelu(float x) {
    return 0.5f * x * (1.0f + fast_erff(x * 0.70710678118654752f));
}

// K1: all input-only precompute (roles by blockIdx)
__global__ void k_prep(const float* __restrict__ dW1, const float* __restrict__ db1,
                       const float* __restrict__ rW1, const float* __restrict__ rb1,
                       const float* __restrict__ ln_g, const float* __restrict__ ln_b,
                       const float* __restrict__ event, const float* __restrict__ We,
                       const float* __restrict__ be,
                       const float* __restrict__ Ws, const float* __restrict__ Wt,
                       const float* __restrict__ Wv,
                       float* __restrict__ WAT, float* __restrict__ WBT,
                       float* __restrict__ WG, float* __restrict__ WBIAS,
                       float* __restrict__ EVH,
                       float* __restrict__ EVSUM, float* __restrict__ E2,
                       float* __restrict__ WsT, float* __restrict__ WtT,
                       float* __restrict__ WvT, int B) {
    int bid = blockIdx.x;
    int tid = threadIdx.x;       // 0..255
    if (bid < 64) {
        // effective-weight transpose: one d per block, lanes over h (coalesced writes)
        int d = bid;
        float gT = ln_g[d], gS = ln_g[64 + d], gD = ln_g[192 + d];
        for (int h = tid; h < H2; h += 256) {
            const float* W1 = (h < H) ? (dW1 + h * SIXD) : (rW1 + (h - H) * SIXD);
            float w3 = W1[192 + d];
            WAT[d * H2 + h] = W1[d] * gT - w3 * gD;
            WBT[d * H2 + h] = W1[64 + d] * gS + w3 * gD;
        }
    } else if (bid < 66) {
        // WG / WBIAS: one h per thread
        int h = (bid - 64) * 256 + tid;
        const float* W1 = (h < H) ? (dW1 + h * SIXD) : (rW1 + (h - H) * SIXD);
        float b1 = (h < H) ? db1[h] : rb1[h - H];
        float sg = 0.f, sb = 0.f;
        #pragma unroll 8
        for (int m = 0; m < SIXD; ++m) {
            float w = W1[m];
            sg = fmaf(w, ln_g[m], sg);
            sb = fmaf(w, ln_b[m], sb);
        }
        WG[h] = sg;
        WBIAS[h] = sb + b1;
    } else if (bid < 66 + 2 * B) {
        // event projection + EVH
        int t = bid - 66;
        int b = t >> 1, half = t & 1;
        __shared__ float egl[64];
        if (tid < 64) {
            int k = tid;
            float acc = be[k];
            const float* evt = event + b * E;
            const float* w = We + k * E;
            for (int e = 0; e < E; ++e) acc = fmaf(w[e], evt[e], acc);
            egl[k] = acc * ln_g[128 + k];
            if (half == 0) {
                float s = acc, s2 = acc * acc;
                for (int o = 32; o > 0; o >>= 1) {
                    s  += __shfl_down(s, o);
                    s2 += __shfl_down(s2, o);
                }
                if (k == 0) { EVSUM[b] = s; E2[b] = s2; }
            }
        }
        __syncthreads();
        int h = half * 256 + tid;
        const float* W1 = (h < H) ? (dW1 + h * SIXD) : (rW1 + (h - H) * SIXD);
        float acc = 0.f;
        #pragma unroll 8
        for (int k = 0; k < 64; ++k) acc = fmaf(W1[128 + k], egl[k], acc);
        EVH[b * H2 + h] = acc;
    } else {
        // transpose Ws/Wt/Wv -> WsT/WtT/WvT  (WT[k][d] = W[d][k])
        int m = bid - (66 + 2 * B);
        const float* W = (m == 0) ? Ws : (m == 1) ? Wt : Wv;
        float* WT = (m == 0) ? WsT : (m == 1) ? WtT : WvT;
        for (int idx = tid; idx < 64 * 64; idx += 256) {
            int d = idx >> 6, k = idx & 63;
            WT[k * 64 + d] = W[idx];
        }
    }
}

// K2: projections + stats + A,B' hidden precompute. Block = (b, n-pair), 512 threads.
__launch_bounds__(512)
__global__ void k_projab(const float* __restrict__ x,
                         const float* __restrict__ WsT, const float* __restrict__ bs,
                         const float* __restrict__ WtT, const float* __restrict__ bt,
                         const float* __restrict__ WvT, const float* __restrict__ bv,
                         const float* __restrict__ EVSUM,
                         const float* __restrict__ WAT, const float* __restrict__ WBT,
                         const float* __restrict__ WG, const float* __restrict__ EVH,
                         float* __restrict__ SRCT, float* __restrict__ TGT,
                         float* __restrict__ VALS,
                         float* __restrict__ S2, float* __restrict__ T2,
                         float* __restrict__ MU,
                         float* __restrict__ ABUF, float* __restrict__ BPT) {
    int bn2 = blockIdx.x;
    int b = bn2 >> 6;
    int np = bn2 & 63;
    int n0 = np * 2, n1 = n0 + 1;
    int tid = threadIdx.x;       // 0..511
    int q = tid >> 6;            // 0..7
    int d = tid & 63;
    __shared__ float xl0[64], xl1[64], sl0[64], sl1[64], tl0[64], tl1[64];
    __shared__ float mus[2];
    if (q == 0) xl0[d] = x[(b * N + n0) * 64 + d];
    else if (q == 1) xl1[d] = x[(b * N + n1) * 64 + d];
    __syncthreads();

    if (q < 6) {
        int which = (q < 3) ? 0 : 1;             // n0 or n1
        int role = (q < 3) ? q : q - 3;          // 0=src 1=tgt 2=val
        const float* xl = which ? xl1 : xl0;
        int n = which ? n1 : n0;
        const float* WT = (role == 0) ? WsT : (role == 1) ? WtT : WvT;
        float bias = (role == 0) ? bs[d] : (role == 1) ? bt[d] : bv[d];
        float acc = bias;
        #pragma unroll 8
        for (int k = 0; k < 64; ++k) acc = fmaf(WT[k * 64 + d], xl[k], acc);
        if (role == 0) {
            (which ? sl1 : sl0)[d] = acc;
            SRCT[(b * 64 + d) * N + n] = acc;
            float ssum = acc, ssq = acc * acc;
            for (int o = 32; o > 0; o >>= 1) {
                ssum += __shfl_down(ssum, o);
                ssq  += __shfl_down(ssq, o);
            }
            if (d == 0) {
                S2[b * N + n] = ssq;
                float mu = (2.f * ssum + EVSUM[b]) * INV_SIXD;
                MU[b * N + n] = mu;
                mus[which] = mu;
            }
        } else if (role == 1) {
            (which ? tl1 : tl0)[d] = acc;
            TGT[(b * N + n) * 64 + d] = acc;
            float tsq = acc * acc;
            for (int o = 32; o > 0; o >>= 1) tsq += __shfl_down(tsq, o);
            if (d == 0) T2[b * N + n] = tsq;
        } else {
            VALS[(b * N + n) * 64 + d] = acc;
        }
    }
    __syncthreads();

    int h = tid;                 // one h per thread
    float a0 = 0.f, a1 = 0.f, b0 = 0.f, b1 = 0.f;
    #pragma unroll 8
    for (int k = 0; k < 64; ++k) {
        float wa = WAT[k * H2 + h];
        float wb = WBT[k * H2 + h];
        a0 = fmaf(wa, tl0[k], a0);
        a1 = fmaf(wa, tl1[k], a1);
        b0 = fmaf(wb, sl0[k], b0);
        b1 = fmaf(wb, sl1[k], b1);
    }
    float evh = EVH[b * H2 + h];
    float wg = WG[h];
    ABUF[(b * N + n0) * H2 + h] = a0;
    ABUF[(b * N + n1) * H2 + h] = a1;
    BPT[(b * H2 + h) * N + n0] = b0 + evh - mus[0] * wg;
    BPT[(b * H2 + h) * N + n1] = b1 + evh - mus[1] * wg;
}

// K3: main per-pair kernel. Block = (b,i), 512 threads.
// Phase 2 geometry: q = tid>>4 (32 h-chunks of 16), p = tid&15 (16 j-octets).
__launch_bounds__(512)
__global__ void k_main(const float* __restrict__ SRCT, const float* __restrict__ TGT,
                       const float* __restrict__ VALS,
                       const float* __restrict__ S2, const float* __restrict__ T2,
                       const float* __restrict__ E2, const float* __restrict__ MU,
                       const float* __restrict__ ABUF, const float* __restrict__ BPT,
                       const float* __restrict__ WBIAS,
                       const float* __restrict__ dW2, const float* __restrict__ db2,
                       const float* __restrict__ rW2, const float* __restrict__ rb2,
                       const float* __restrict__ gate_bias,
                       float* __restrict__ out) {
    int bn = blockIdx.x;
    int b = bn >> 7;
    int i = bn & (N - 1);
    int tid = threadIdx.x;       // 0..511
    __shared__ float4 alwb[H2];                    // {Al, wb, w2, 0} per h
    __shared__ float invl[N], dotp[4][N], part[32][N], gl[N];
    __shared__ float accp[8][64], gmp[8];

    // phase 1: src_j . tgt_i partials (TGT read direct from global — L1 broadcast)
    {
        int c = tid >> 7;                          // d-chunk of 16
        int j = tid & (N - 1);
        const float* st = SRCT + b * 64 * N + j;
        const float* tg = TGT + bn * 64;
        float acc = 0.f;
        #pragma unroll
        for (int d = c * 16; d < c * 16 + 16; ++d) acc = fmaf(st[d * N], tg[d], acc);
        dotp[c][j] = acc;
    }
    // stage {Al, wb, w2}
    {
        float al = ABUF[bn * H2 + tid];
        float wb = WBIAS[tid];
        float w2 = (tid < H) ? dW2[tid] : rW2[tid - H];
        alwb[tid] = make_float4(al, wb, w2, 0.f);
    }
    __syncthreads();

    if (tid < N) {
        int j = tid;
        float dot = dotp[0][j] + dotp[1][j] + dotp[2][j] + dotp[3][j];
        float mu = MU[b * N + j];
        float s2 = S2[b * N + j];
        float ms = (2.f * T2[bn] + 2.f * s2 - 2.f * dot + E2[b]) * INV_SIXD;
        invl[j] = rsqrtf(ms - mu * mu + 1e-5f);
    }
    __syncthreads();

    // phase 2: gelu h-loop. thread (q,p): h in [q*16, q*16+16), j = 8p..8p+7
    // 8 independent accumulator chains per thread (all indices compile-time).
    {
        int q = tid >> 4;
        int p = tid & 15;
        float4 ia = *(const float4*)&invl[8 * p];
        float4 ib = *(const float4*)&invl[8 * p + 4];
        const float* Bp = BPT + (b * H2 + q * 16) * N + 8 * p;
        int hbase = q * 16;
        float acc0 = 0.f, acc1 = 0.f, acc2 = 0.f, acc3 = 0.f;
        float acc4 = 0.f, acc5 = 0.f, acc6 = 0.f, acc7 = 0.f;
        #pragma unroll
        for (int hh = 0; hh < 16; ++hh) {
            float4 bp0 = *(const float4*)&Bp[hh * N];
            float4 bp1 = *(const float4*)&Bp[hh * N + 4];
            float4 aw = alwb[hbase + hh];
            float pre0 = fmaf(ia.x, aw.x + bp0.x, aw.y);
            float pre1 = fmaf(ia.y, aw.x + bp0.y, aw.y);
            float pre2 = fmaf(ia.z, aw.x + bp0.z, aw.y);
            float pre3 = fmaf(ia.w, aw.x + bp0.w, aw.y);
            float pre4 = fmaf(ib.x, aw.x + bp1.x, aw.y);
            float pre5 = fmaf(ib.y, aw.x + bp1.y, aw.y);
            float pre6 = fmaf(ib.z, aw.x + bp1.z, aw.y);
            float pre7 = fmaf(ib.w, aw.x + bp1.w, aw.y);
            acc0 = fmaf(fast_gelu(pre0), aw.z, acc0);
            acc1 = fmaf(fast_gelu(pre1), aw.z, acc1);
            acc2 = fmaf(fast_gelu(pre2), aw.z, acc2);
            acc3 = fmaf(fast_gelu(pre3), aw.z, acc3);
            acc4 = fmaf(fast_gelu(pre4), aw.z, acc4);
            acc5 = fmaf(fast_gelu(pre5), aw.z, acc5);
            acc6 = fmaf(fast_gelu(pre6), aw.z, acc6);
            acc7 = fmaf(fast_gelu(pre7), aw.z, acc7);
        }
        *(float4*)&part[q][8 * p]     = make_float4(acc0, acc1, acc2, acc3);
        *(float4*)&part[q][8 * p + 4] = make_float4(acc4, acc5, acc6, acc7);
    }
    __syncthreads();

    if (tid < N) {
        int j = tid;
        float drive = db2[0], resist = rb2[0];
        #pragma unroll
        for (int qq = 0; qq < 16; ++qq)  drive  += part[qq][j];
        #pragma unroll
        for (int qq = 16; qq < 32; ++qq) resist += part[qq][j];
        float sp = (resist > 20.f) ? resist : __logf(1.f + __expf(resist));
        float energy = drive / (sp + 1e-6f);
        energy = fminf(fmaxf(energy, -3.f), 3.f);
        float gate = __builtin_amdgcn_rcpf(1.f + __expf(-(energy + gate_bias[0])));
        if (j == i) gate = 0.f;
        gl[j] = gate;
    }
    __syncthreads();

    // aggregation: pc = j-chunk (8 chunks of 16), dd = output dim
    {
        int pc = tid >> 6;
        int dd = tid & 63;
        float va = 0.f, gm = 0.f;
        const float* v = VALS + b * N * 64 + dd;
        #pragma unroll
        for (int jj = pc * 16; jj < pc * 16 + 16; ++jj) {
            float g = gl[jj];
            gm += g;
            va = fmaf(g, v[jj * 64], va);
        }
        accp[pc][dd] = va;
        if (dd == 0) gmp[pc] = gm;
    }
    __syncthreads();

    if (tid < 64) {
        float sum = 0.f, gmsum = 0.f;
        #pragma unroll
        for (int pp = 0; pp < 8; ++pp) {
            sum += accp[pp][tid];
            gmsum += gmp[pp];
        }
        gmsum = fmaxf(gmsum, 1e-6f);
        out[bn * 64 + tid] = sum / gmsum;
    }
}

extern "C" void kernel_launch(void* const* d_in, const int* in_sizes, int n_in,
                              void* d_out, int out_size, void* d_ws, size_t ws_size,
                              hipStream_t stream) {
    const float* x        = (const float*)d_in[0];
    const float* event    = (const float*)d_in[1];
    const float* We       = (const float*)d_in[2];
    const float* be       = (const float*)d_in[3];
    const float* Ws       = (const float*)d_in[4];
    const float* bs       = (const float*)d_in[5];
    const float* Wt       = (const float*)d_in[6];
    const float* bt       = (const float*)d_in[7];
    const float* Wv       = (const float*)d_in[8];
    const float* bv       = (const float*)d_in[9];
    const float* ln_g     = (const float*)d_in[10];
    const float* ln_b     = (const float*)d_in[11];
    const float* dW1      = (const float*)d_in[12];
    const float* db1      = (const float*)d_in[13];
    const float* dW2      = (const float*)d_in[14];
    const float* db2      = (const float*)d_in[15];
    const float* rW1      = (const float*)d_in[16];
    const float* rb1      = (const float*)d_in[17];
    const float* rW2      = (const float*)d_in[18];
    const float* rb2      = (const float*)d_in[19];
    const float* gate_b   = (const float*)d_in[20];

    const int B = in_sizes[0] / (N * D);   // 8

    float* ws = (float*)d_ws;
    float* EVSUM = ws;             ws += B;
    float* E2    = ws;             ws += B;
    float* SRCT  = ws;             ws += B * 64 * N;
    float* TGT   = ws;             ws += B * N * 64;
    float* VALS  = ws;             ws += B * N * 64;
    float* S2    = ws;             ws += B * N;
    float* T2    = ws;             ws += B * N;
    float* MU    = ws;             ws += B * N;
    float* WAT   = ws;             ws += 64 * H2;
    float* WBT   = ws;             ws += 64 * H2;
    float* WG    = ws;             ws += H2;
    float* WBIAS = ws;             ws += H2;
    float* EVH   = ws;             ws += B * H2;
    float* WsT   = ws;             ws += 64 * 64;
    float* WtT   = ws;             ws += 64 * 64;
    float* WvT   = ws;             ws += 64 * 64;
    float* ABUF  = ws;             ws += B * N * H2;
    float* BPT   = ws;             ws += B * H2 * N;

    hipLaunchKernelGGL(k_prep, dim3(66 + 2 * B + 3), dim3(256), 0, stream,
                       dW1, db1, rW1, rb1, ln_g, ln_b, event, We, be,
                       Ws, Wt, Wv,
                       WAT, WBT, WG, WBIAS, EVH, EVSUM, E2, WsT, WtT, WvT, B);
    hipLaunchKernelGGL(k_projab, dim3(B * 64), dim3(512), 0, stream,
                       x, WsT, bs, WtT, bt, WvT, bv, EVSUM,
                       WAT, WBT, WG, EVH,
                       SRCT, TGT, VALS, S2, T2, MU, ABUF, BPT);
    hipLaunchKernelGGL(k_main, dim3(B * N), dim3(512), 0, stream,
                       SRCT, TGT, VALS, S2, T2, E2, MU, ABUF, BPT, WBIAS,
                       dW2, db2, rW2, rb2, gate_b, (float*)d_out);
}

// Round 9
// 157.584 us; speedup vs baseline: 1.1223x; 1.1223x over previous
//
#include <hip/hip_runtime.h>
#include <math.h>

// Shapes (fixed by the reference setup)
#define D 64
#define E 128
#define H 256
#define N 128
#define H2 512          // drive hidden + resistance hidden concatenated
#define SIXD 384
#define INV_SIXD 0.0026041666666666665f

__device__ __forceinline__ float fast_erff(float x) {
    float ax = fabsf(x);
    float t = __builtin_amdgcn_rcpf(fmaf(0.3275911f, ax, 1.0f));
    float p = t * fmaf(t, fmaf(t, fmaf(t, fmaf(t, 1.061405429f, -1.453152027f),
                               1.421413741f), -0.284496736f), 0.254829592f);
    float r = fmaf(-p, __expf(-ax * ax), 1.0f);
    return copysignf(r, x);
}

__device__ __forceinline__ float fast_gelu(float x) {
    return 0.5f * x * (1.0f + fast_erff(x * 0.70710678118654752f));
}

// K1: all input-only precompute (roles by blockIdx)
__global__ void k_prep(const float* __restrict__ dW1, const float* __restrict__ db1,
                       const float* __restrict__ rW1, const float* __restrict__ rb1,
                       const float* __restrict__ ln_g, const float* __restrict__ ln_b,
                       const float* __restrict__ event, const float* __restrict__ We,
                       const float* __restrict__ be,
                       const float* __restrict__ Ws, const float* __restrict__ Wt,
                       const float* __restrict__ Wv,
                       float* __restrict__ WAT, float* __restrict__ WBT,
                       float* __restrict__ WG, float* __restrict__ WBIAS,
                       float* __restrict__ EVH,
                       float* __restrict__ EVSUM, float* __restrict__ E2,
                       float* __restrict__ WsT, float* __restrict__ WtT,
                       float* __restrict__ WvT, int B) {
    int bid = blockIdx.x;
    int tid = threadIdx.x;       // 0..255
    if (bid < 64) {
        // effective-weight transpose: one d per block, lanes over h (coalesced writes)
        int d = bid;
        float gT = ln_g[d], gS = ln_g[64 + d], gD = ln_g[192 + d];
        for (int h = tid; h < H2; h += 256) {
            const float* W1 = (h < H) ? (dW1 + h * SIXD) : (rW1 + (h - H) * SIXD);
            float w3 = W1[192 + d];
            WAT[d * H2 + h] = W1[d] * gT - w3 * gD;
            WBT[d * H2 + h] = W1[64 + d] * gS + w3 * gD;
        }
    } else if (bid < 66) {
        // WG / WBIAS: one h per thread
        int h = (bid - 64) * 256 + tid;
        const float* W1 = (h < H) ? (dW1 + h * SIXD) : (rW1 + (h - H) * SIXD);
        float b1 = (h < H) ? db1[h] : rb1[h - H];
        float sg = 0.f, sb = 0.f;
        #pragma unroll 8
        for (int m = 0; m < SIXD; ++m) {
            float w = W1[m];
            sg = fmaf(w, ln_g[m], sg);
            sb = fmaf(w, ln_b[m], sb);
        }
        WG[h] = sg;
        WBIAS[h] = sb + b1;
    } else if (bid < 66 + 2 * B) {
        // event projection + EVH
        int t = bid - 66;
        int b = t >> 1, half = t & 1;
        __shared__ float egl[64];
        if (tid < 64) {
            int k = tid;
            float acc = be[k];
            const float* evt = event + b * E;
            const float* w = We + k * E;
            for (int e = 0; e < E; ++e) acc = fmaf(w[e], evt[e], acc);
            egl[k] = acc * ln_g[128 + k];
            if (half == 0) {
                float s = acc, s2 = acc * acc;
                for (int o = 32; o > 0; o >>= 1) {
                    s  += __shfl_down(s, o);
                    s2 += __shfl_down(s2, o);
                }
                if (k == 0) { EVSUM[b] = s; E2[b] = s2; }
            }
        }
        __syncthreads();
        int h = half * 256 + tid;
        const float* W1 = (h < H) ? (dW1 + h * SIXD) : (rW1 + (h - H) * SIXD);
        float acc = 0.f;
        #pragma unroll 8
        for (int k = 0; k < 64; ++k) acc = fmaf(W1[128 + k], egl[k], acc);
        EVH[b * H2 + h] = acc;
    } else {
        // transpose Ws/Wt/Wv -> WsT/WtT/WvT  (WT[k][d] = W[d][k])
        int m = bid - (66 + 2 * B);
        const float* W = (m == 0) ? Ws : (m == 1) ? Wt : Wv;
        float* WT = (m == 0) ? WsT : (m == 1) ? WtT : WvT;
        for (int idx = tid; idx < 64 * 64; idx += 256) {
            int d = idx >> 6, k = idx & 63;
            WT[k * 64 + d] = W[idx];
        }
    }
}

// K2: projections + stats + A,B' hidden precompute. Block = (b, n-pair), 512 threads.
__launch_bounds__(512)
__global__ void k_projab(const float* __restrict__ x,
                         const float* __restrict__ WsT, const float* __restrict__ bs,
                         const float* __restrict__ WtT, const float* __restrict__ bt,
                         const float* __restrict__ WvT, const float* __restrict__ bv,
                         const float* __restrict__ EVSUM,
                         const float* __restrict__ WAT, const float* __restrict__ WBT,
                         const float* __restrict__ WG, const float* __restrict__ EVH,
                         float* __restrict__ SRCT, float* __restrict__ TGT,
                         float* __restrict__ VALS,
                         float* __restrict__ S2, float* __restrict__ T2,
                         float* __restrict__ MU,
                         float* __restrict__ ABUF, float* __restrict__ BPT) {
    int bn2 = blockIdx.x;
    int b = bn2 >> 6;
    int np = bn2 & 63;
    int n0 = np * 2, n1 = n0 + 1;
    int tid = threadIdx.x;       // 0..511
    int q = tid >> 6;            // 0..7
    int d = tid & 63;
    __shared__ float xl0[64], xl1[64], sl0[64], sl1[64], tl0[64], tl1[64];
    __shared__ float mus[2];
    if (q == 0) xl0[d] = x[(b * N + n0) * 64 + d];
    else if (q == 1) xl1[d] = x[(b * N + n1) * 64 + d];
    __syncthreads();

    if (q < 6) {
        int which = (q < 3) ? 0 : 1;             // n0 or n1
        int role = (q < 3) ? q : q - 3;          // 0=src 1=tgt 2=val
        const float* xl = which ? xl1 : xl0;
        int n = which ? n1 : n0;
        const float* WT = (role == 0) ? WsT : (role == 1) ? WtT : WvT;
        float bias = (role == 0) ? bs[d] : (role == 1) ? bt[d] : bv[d];
        float acc = bias;
        #pragma unroll 8
        for (int k = 0; k < 64; ++k) acc = fmaf(WT[k * 64 + d], xl[k], acc);
        if (role == 0) {
            (which ? sl1 : sl0)[d] = acc;
            SRCT[(b * 64 + d) * N + n] = acc;
            float ssum = acc, ssq = acc * acc;
            for (int o = 32; o > 0; o >>= 1) {
                ssum += __shfl_down(ssum, o);
                ssq  += __shfl_down(ssq, o);
            }
            if (d == 0) {
                S2[b * N + n] = ssq;
                float mu = (2.f * ssum + EVSUM[b]) * INV_SIXD;
                MU[b * N + n] = mu;
                mus[which] = mu;
            }
        } else if (role == 1) {
            (which ? tl1 : tl0)[d] = acc;
            TGT[(b * N + n) * 64 + d] = acc;
            float tsq = acc * acc;
            for (int o = 32; o > 0; o >>= 1) tsq += __shfl_down(tsq, o);
            if (d == 0) T2[b * N + n] = tsq;
        } else {
            VALS[(b * N + n) * 64 + d] = acc;
        }
    }
    __syncthreads();

    int h = tid;                 // one h per thread
    float a0 = 0.f, a1 = 0.f, b0 = 0.f, b1 = 0.f;
    #pragma unroll 8
    for (int k = 0; k < 64; ++k) {
        float wa = WAT[k * H2 + h];
        float wb = WBT[k * H2 + h];
        a0 = fmaf(wa, tl0[k], a0);
        a1 = fmaf(wa, tl1[k], a1);
        b0 = fmaf(wb, sl0[k], b0);
        b1 = fmaf(wb, sl1[k], b1);
    }
    float evh = EVH[b * H2 + h];
    float wg = WG[h];
    ABUF[(b * N + n0) * H2 + h] = a0;
    ABUF[(b * N + n1) * H2 + h] = a1;
    BPT[(b * H2 + h) * N + n0] = b0 + evh - mus[0] * wg;
    BPT[(b * H2 + h) * N + n1] = b1 + evh - mus[1] * wg;
}

// K3: main per-pair kernel. Block = (b,i), 512 threads.
// Phase 2 geometry: q = tid>>5 (16 h-chunks of 32), p = tid&31 (32 j-quads).
__launch_bounds__(512)
__global__ void k_main(const float* __restrict__ SRCT, const float* __restrict__ TGT,
                       const float* __restrict__ VALS,
                       const float* __restrict__ S2, const float* __restrict__ T2,
                       const float* __restrict__ E2, const float* __restrict__ MU,
                       const float* __restrict__ ABUF, const float* __restrict__ BPT,
                       const float* __restrict__ WBIAS,
                       const float* __restrict__ dW2, const float* __restrict__ db2,
                       const float* __restrict__ rW2, const float* __restrict__ rb2,
                       const float* __restrict__ gate_bias,
                       float* __restrict__ out) {
    int bn = blockIdx.x;
    int b = bn >> 7;
    int i = bn & (N - 1);
    int tid = threadIdx.x;       // 0..511
    __shared__ float4 alwb[H2];                    // {Al, wb, w2, 0} per h
    __shared__ float invl[N], dotp[4][N], part[16][N], gl[N];
    __shared__ float accp[8][64], gmp[8];

    // phase 1: src_j . tgt_i partials (TGT read direct from global — L1 broadcast)
    {
        int c = tid >> 7;                          // d-chunk of 16
        int j = tid & (N - 1);
        const float* st = SRCT + b * 64 * N + j;
        const float* tg = TGT + bn * 64;
        float acc = 0.f;
        #pragma unroll
        for (int d = c * 16; d < c * 16 + 16; ++d) acc = fmaf(st[d * N], tg[d], acc);
        dotp[c][j] = acc;
    }
    // stage {Al, wb, w2}
    {
        float al = ABUF[bn * H2 + tid];
        float wb = WBIAS[tid];
        float w2 = (tid < H) ? dW2[tid] : rW2[tid - H];
        alwb[tid] = make_float4(al, wb, w2, 0.f);
    }
    __syncthreads();

    if (tid < N) {
        int j = tid;
        float dot = dotp[0][j] + dotp[1][j] + dotp[2][j] + dotp[3][j];
        float mu = MU[b * N + j];
        float s2 = S2[b * N + j];
        float ms = (2.f * T2[bn] + 2.f * s2 - 2.f * dot + E2[b]) * INV_SIXD;
        invl[j] = rsqrtf(ms - mu * mu + 1e-5f);
    }
    __syncthreads();

    // phase 2: gelu h-loop. thread (q,p): h in [q*32, q*32+32), j = 4p..4p+3
    {
        int q = tid >> 5;
        int p = tid & 31;
        float4 inv4 = *(const float4*)&invl[4 * p];
        const float* Bp = BPT + (b * H2 + q * 32) * N + 4 * p;
        int hbase = q * 32;
        float acc0 = 0.f, acc1 = 0.f, acc2 = 0.f, acc3 = 0.f;
        #pragma unroll 8
        for (int hh = 0; hh < 32; ++hh) {
            float4 bp = *(const float4*)&Bp[hh * N];
            float4 aw = alwb[hbase + hh];
            float pre0 = fmaf(inv4.x, aw.x + bp.x, aw.y);
            float pre1 = fmaf(inv4.y, aw.x + bp.y, aw.y);
            float pre2 = fmaf(inv4.z, aw.x + bp.z, aw.y);
            float pre3 = fmaf(inv4.w, aw.x + bp.w, aw.y);
            acc0 = fmaf(fast_gelu(pre0), aw.z, acc0);
            acc1 = fmaf(fast_gelu(pre1), aw.z, acc1);
            acc2 = fmaf(fast_gelu(pre2), aw.z, acc2);
            acc3 = fmaf(fast_gelu(pre3), aw.z, acc3);
        }
        *(float4*)&part[q][4 * p] = make_float4(acc0, acc1, acc2, acc3);
    }
    __syncthreads();

    if (tid < N) {
        int j = tid;
        float drive = db2[0], resist = rb2[0];
        #pragma unroll
        for (int qq = 0; qq < 8; ++qq)  drive  += part[qq][j];
        #pragma unroll
        for (int qq = 8; qq < 16; ++qq) resist += part[qq][j];
        float sp = (resist > 20.f) ? resist : __logf(1.f + __expf(resist));
        float energy = drive / (sp + 1e-6f);
        energy = fminf(fmaxf(energy, -3.f), 3.f);
        float gate = __builtin_amdgcn_rcpf(1.f + __expf(-(energy + gate_bias[0])));
        if (j == i) gate = 0.f;
        gl[j] = gate;
    }
    __syncthreads();

    // aggregation: pc = j-chunk (8 chunks of 16), dd = output dim
    {
        int pc = tid >> 6;
        int dd = tid & 63;
        float va = 0.f, gm = 0.f;
        const float* v = VALS + b * N * 64 + dd;
        #pragma unroll
        for (int jj = pc * 16; jj < pc * 16 + 16; ++jj) {
            float g = gl[jj];
            gm += g;
            va = fmaf(g, v[jj * 64], va);
        }
        accp[pc][dd] = va;
        if (dd == 0) gmp[pc] = gm;
    }
    __syncthreads();

    if (tid < 64) {
        float sum = 0.f, gmsum = 0.f;
        #pragma unroll
        for (int pp = 0; pp < 8; ++pp) {
            sum += accp[pp][tid];
            gmsum += gmp[pp];
        }
        gmsum = fmaxf(gmsum, 1e-6f);
        out[bn * 64 + tid] = sum / gmsum;
    }
}

extern "C" void kernel_launch(void* const* d_in, const int* in_sizes, int n_in,
                              void* d_out, int out_size, void* d_ws, size_t ws_size,
                              hipStream_t stream) {
    const float* x        = (const float*)d_in[0];
    const float* event    = (const float*)d_in[1];
    const float* We       = (const float*)d_in[2];
    const float* be       = (const float*)d_in[3];
    const float* Ws       = (const float*)d_in[4];
    const float* bs       = (const float*)d_in[5];
    const float* Wt       = (const float*)d_in[6];
    const float* bt       = (const float*)d_in[7];
    const float* Wv       = (const float*)d_in[8];
    const float* bv       = (const float*)d_in[9];
    const float* ln_g     = (const float*)d_in[10];
    const float* ln_b     = (const float*)d_in[11];
    const float* dW1      = (const float*)d_in[12];
    const float* db1      = (const float*)d_in[13];
    const float* dW2      = (const float*)d_in[14];
    const float* db2      = (const float*)d_in[15];
    const float* rW1      = (const float*)d_in[16];
    const float* rb1      = (const float*)d_in[17];
    const float* rW2      = (const float*)d_in[18];
    const float* rb2      = (const float*)d_in[19];
    const float* gate_b   = (const float*)d_in[20];

    const int B = in_sizes[0] / (N * D);   // 8

    float* ws = (float*)d_ws;
    float* EVSUM = ws;             ws += B;
    float* E2    = ws;             ws += B;
    float* SRCT  = ws;             ws += B * 64 * N;
    float* TGT   = ws;             ws += B * N * 64;
    float* VALS  = ws;             ws += B * N * 64;
    float* S2    = ws;             ws += B * N;
    float* T2    = ws;             ws += B * N;
    float* MU    = ws;             ws += B * N;
    float* WAT   = ws;             ws += 64 * H2;
    float* WBT   = ws;             ws += 64 * H2;
    float* WG    = ws;             ws += H2;
    float* WBIAS = ws;             ws += H2;
    float* EVH   = ws;             ws += B * H2;
    float* WsT   = ws;             ws += 64 * 64;
    float* WtT   = ws;             ws += 64 * 64;
    float* WvT   = ws;             ws += 64 * 64;
    float* ABUF  = ws;             ws += B * N * H2;
    float* BPT   = ws;             ws += B * H2 * N;

    hipLaunchKernelGGL(k_prep, dim3(66 + 2 * B + 3), dim3(256), 0, stream,
                       dW1, db1, rW1, rb1, ln_g, ln_b, event, We, be,
                       Ws, Wt, Wv,
                       WAT, WBT, WG, WBIAS, EVH, EVSUM, E2, WsT, WtT, WvT, B);
    hipLaunchKernelGGL(k_projab, dim3(B * 64), dim3(512), 0, stream,
                       x, WsT, bs, WtT, bt, WvT, bv, EVSUM,
                       WAT, WBT, WG, EVH,
                       SRCT, TGT, VALS, S2, T2, MU, ABUF, BPT);
    hipLaunchKernelGGL(k_main, dim3(B * N), dim3(512), 0, stream,
                       SRCT, TGT, VALS, S2, T2, E2, MU, ABUF, BPT, WBIAS,
                       dW2, db2, rW2, rb2, gate_b, (float*)d_out);
}